// Round 2
// baseline (154.702 us; speedup 1.0000x reference)
//
#include <hip/hip_runtime.h>

#define H 4096
#define W 4096
#define TH 32          // rows per edge block
#define BX 256         // threads per block
#define GX 4           // 4096 cols / (256 thr * 4 cols)
#define GY (H / TH)    // 128
#define NEDGE (GX * GY)   // 512 edge blocks
#define NKPB 16           // keypoint blocks (64 kp each, 1024 total)

#define MASK_W 1.0f
#define KPT_W 0.5f

struct RowData { float v0, v1, v2, v3, lf, rf; };
struct Prep { float dx0, dx1, dx2, dx3, s0, s1, s2, s3; };

__device__ __forceinline__ RowData loadrow(const float* __restrict__ img, int r, int c) {
    RowData rd;
    if ((unsigned)r < (unsigned)H) {
        const float* p = img + (size_t)r * W + c;
        float4 v = *(const float4*)p;
        rd.v0 = v.x; rd.v1 = v.y; rd.v2 = v.z; rd.v3 = v.w;
        rd.lf = (c == 0) ? 0.f : p[-1];
        rd.rf = (c + 4 == W) ? 0.f : p[4];
    } else {
        rd.v0 = rd.v1 = rd.v2 = rd.v3 = rd.lf = rd.rf = 0.f;
    }
    return rd;
}

__device__ __forceinline__ Prep prep(const RowData& rd) {
    Prep o;
    // elements: e[-1]=lf, e0..e3 = v0..v3, e4 = rf
    o.dx0 = rd.v1 - rd.lf;
    o.dx1 = rd.v2 - rd.v0;
    o.dx2 = rd.v3 - rd.v1;
    o.dx3 = rd.rf - rd.v2;
    o.s0 = __fmaf_rn(2.f, rd.v0, rd.lf + rd.v1);
    o.s1 = __fmaf_rn(2.f, rd.v1, rd.v0 + rd.v2);
    o.s2 = __fmaf_rn(2.f, rd.v2, rd.v1 + rd.v3);
    o.s3 = __fmaf_rn(2.f, rd.v3, rd.v2 + rd.rf);
    return o;
}

__device__ __forceinline__ float edge1(float dxA, float dxB, float dxC, float sA, float sC) {
    float ex = dxA + __fmaf_rn(2.f, dxB, dxC);
    float ey = sC - sA;
    return sqrtf(__fmaf_rn(ex, ex, ey * ey));
}

__global__ __launch_bounds__(BX) void fused_kernel(const float* __restrict__ pred,
                                                   const float* __restrict__ targ,
                                                   const float* __restrict__ kp,
                                                   float* __restrict__ ws) {
    int bid = blockIdx.x;

    if (bid < NEDGE) {
        // ======================= edge-loss tile =======================
        int gx = bid & (GX - 1);
        int gy = bid >> 2;           // log2(GX)=2
        int c = gx * (BX * 4) + threadIdx.x * 4;
        int r0 = gy * TH;

        Prep pA = prep(loadrow(pred, r0 - 1, c));
        Prep pB = prep(loadrow(pred, r0,     c));
        Prep tA = prep(loadrow(targ, r0 - 1, c));
        Prep tB = prep(loadrow(targ, r0,     c));
        RowData pn = loadrow(pred, r0 + 1, c);
        RowData tn = loadrow(targ, r0 + 1, c);

        float acc = 0.f;
        for (int r = r0; r < r0 + TH; ++r) {
            RowData pc = pn, tc = tn;
            if (r < r0 + TH - 1) {              // prefetch row r+2 (uniform branch)
                pn = loadrow(pred, r + 2, c);
                tn = loadrow(targ, r + 2, c);
            }
            Prep pC = prep(pc);
            Prep tC = prep(tc);

            float pe, te, d;
            pe = edge1(pA.dx0, pB.dx0, pC.dx0, pA.s0, pC.s0);
            te = edge1(tA.dx0, tB.dx0, tC.dx0, tA.s0, tC.s0);
            d = pe - te; acc = __fmaf_rn(d, d, acc);
            pe = edge1(pA.dx1, pB.dx1, pC.dx1, pA.s1, pC.s1);
            te = edge1(tA.dx1, tB.dx1, tC.dx1, tA.s1, tC.s1);
            d = pe - te; acc = __fmaf_rn(d, d, acc);
            pe = edge1(pA.dx2, pB.dx2, pC.dx2, pA.s2, pC.s2);
            te = edge1(tA.dx2, tB.dx2, tC.dx2, tA.s2, tC.s2);
            d = pe - te; acc = __fmaf_rn(d, d, acc);
            pe = edge1(pA.dx3, pB.dx3, pC.dx3, pA.s3, pC.s3);
            te = edge1(tA.dx3, tB.dx3, tC.dx3, tA.s3, tC.s3);
            d = pe - te; acc = __fmaf_rn(d, d, acc);

            pA = pB; pB = pC;
            tA = tB; tB = tC;
        }

        // wave reduce (width 64)
        #pragma unroll
        for (int m = 32; m; m >>= 1) acc += __shfl_xor(acc, m);

        __shared__ float wsum[BX / 64];
        if ((threadIdx.x & 63) == 0) wsum[threadIdx.x >> 6] = acc;
        __syncthreads();
        if (threadIdx.x == 0) {
            float s = 0.f;
            #pragma unroll
            for (int i = 0; i < BX / 64; ++i) s += wsum[i];
            ws[bid] = s;
        }
    } else {
        // ======================= keypoint block =======================
        // blocks NEDGE..NEDGE+NKPB-1; only first wave (64 threads) active
        int t = threadIdx.x;
        if (t >= 64) return;
        int k = (bid - NEDGE) * 64 + t;        // keypoint index 0..1023

        float gx = kp[2 * k];
        float gy = kp[2 * k + 1];
        float x = (gx + 1.f) * (W * 0.5f) - 0.5f;
        float y = (gy + 1.f) * (H * 0.5f) - 0.5f;
        float fx0 = floorf(x), fy0 = floorf(y);
        int x0 = (int)fx0, y0 = (int)fy0;
        int x1 = x0 + 1, y1 = y0 + 1;
        float wx1 = x - fx0, wx0 = 1.f - wx1;
        float wy1 = y - fy0, wy0 = 1.f - wy1;

        // 6x6 pred_seg patch around (y0, x0), zero-padded
        float sg[6][6];
        #pragma unroll
        for (int i = 0; i < 6; ++i) {
            int rr = y0 - 2 + i;
            #pragma unroll
            for (int j = 0; j < 6; ++j) {
                int cc = x0 - 2 + j;
                bool ok = (rr >= 0) & (rr < H) & (cc >= 0) & (cc < W);
                sg[i][j] = ok ? pred[(size_t)rr * W + cc] : 0.f;
            }
        }

        // 4x4 pred_edge for rows y0-1..y0+2, cols x0-1..x0+2 (0 when OOB)
        float e[4][4];
        #pragma unroll
        for (int i = 0; i < 4; ++i) {
            int rr = y0 - 1 + i;
            #pragma unroll
            for (int j = 0; j < 4; ++j) {
                int cc = x0 - 1 + j;
                if (rr < 0 || rr >= H || cc < 0 || cc >= W) { e[i][j] = 0.f; continue; }
                float ex = (sg[i][j + 2] - sg[i][j])
                         + 2.f * (sg[i + 1][j + 2] - sg[i + 1][j])
                         + (sg[i + 2][j + 2] - sg[i + 2][j]);
                float ey = (sg[i + 2][j] + 2.f * sg[i + 2][j + 1] + sg[i + 2][j + 2])
                         - (sg[i][j] + 2.f * sg[i][j + 1] + sg[i][j + 2]);
                e[i][j] = sqrtf(__fmaf_rn(ex, ex, ey * ey));
            }
        }

        // 2x2 distance-map values (3x3 box over pred_edge), zero-padded conv
        float dmap[2][2];
        #pragma unroll
        for (int a = 0; a < 2; ++a) {
            #pragma unroll
            for (int b = 0; b < 2; ++b) {
                float s = 0.f;
                #pragma unroll
                for (int i = 0; i < 3; ++i)
                    #pragma unroll
                    for (int j = 0; j < 3; ++j) s += e[a + i][b + j];
                dmap[a][b] = s;
            }
        }

        bool vx0 = (x0 >= 0) & (x0 < W), vx1 = (x1 >= 0) & (x1 < W);
        bool vy0 = (y0 >= 0) & (y0 < H), vy1 = (y1 >= 0) & (y1 < H);
        float v00 = (vx0 & vy0) ? dmap[0][0] : 0.f;
        float v01 = (vx1 & vy0) ? dmap[0][1] : 0.f;
        float v10 = (vx0 & vy1) ? dmap[1][0] : 0.f;
        float v11 = (vx1 & vy1) ? dmap[1][1] : 0.f;
        float kd = wx0 * wy0 * v00 + wx1 * wy0 * v01
                 + wx0 * wy1 * v10 + wx1 * wy1 * v11;

        // wave reduce 64 kd values
        #pragma unroll
        for (int m = 32; m; m >>= 1) kd += __shfl_xor(kd, m);
        if (t == 0) ws[NEDGE + (bid - NEDGE)] = kd;
    }
}

__global__ __launch_bounds__(64) void final_kernel(const float* __restrict__ ws,
                                                   float* __restrict__ out) {
    int t = threadIdx.x;
    float es = 0.f;
    #pragma unroll
    for (int i = 0; i < NEDGE / 64; ++i) es += ws[t + i * 64];
    float ks = (t < NKPB) ? ws[NEDGE + t] : 0.f;

    #pragma unroll
    for (int m = 32; m; m >>= 1) {
        es += __shfl_xor(es, m);
        ks += __shfl_xor(ks, m);
    }
    if (t == 0) {
        float edge_loss = es * (1.f / ((float)H * (float)W));
        float constraint_loss = ks * (1.f / 1024.f);
        out[0] = MASK_W * edge_loss + KPT_W * constraint_loss;
    }
}

extern "C" void kernel_launch(void* const* d_in, const int* in_sizes, int n_in,
                              void* d_out, int out_size, void* d_ws, size_t ws_size,
                              hipStream_t stream) {
    const float* kp   = (const float*)d_in[0];
    const float* pred = (const float*)d_in[2];
    const float* targ = (const float*)d_in[3];
    float* out = (float*)d_out;
    float* ws  = (float*)d_ws;

    fused_kernel<<<NEDGE + NKPB, BX, 0, stream>>>(pred, targ, kp, ws);
    final_kernel<<<1, 64, 0, stream>>>(ws, out);
}